// Round 5
// baseline (527.701 us; speedup 1.0000x reference)
//
#include <hip/hip_runtime.h>
#include <hip/hip_cooperative_groups.h>

namespace cg = cooperative_groups;

#define BB 2
#define NN 16384
#define CC 64
#define SS 4096
#define KK 32
#define R2 0.16f   // RADIUS^2

// spatial grid: cell = RADIUS, 24^3 cells covering [-4.8, 4.8] (clamped; the
// clamp is monotone so the 3x3x3 neighborhood remains a superset of the ball
// for ANY input magnitude — tail points just pile into edge cells)
#define GD   24
#define GC   (GD * GD * GD)       // 13824 cells per batch
#define GCP  (GC + 4)             // offs stride (GC+1 used)
#define CAP  512                  // per-wave hit-list capacity (max expected ~360)
#define CAPL (CAP / 64)           // 8 register chunks for selection

#define GRID  1024                // cooperative grid: 4 blocks/CU guaranteed
#define TILES 2                   // 2048 tiles / 1024 blocks

typedef __bf16 bf16x8 __attribute__((ext_vector_type(8)));
typedef float  f32x4  __attribute__((ext_vector_type(4)));

#define MFMA(a, b, c) __builtin_amdgcn_mfma_f32_16x16x32_bf16((a), (b), (c), 0, 0, 0)

static __device__ __forceinline__ ushort f2bf(float f) {
    __bf16 h = (__bf16)f;
    return *(ushort*)&h;
}

static __device__ __forceinline__ int cellc(float x) {
    int i = (int)floorf(x * 2.5f + 12.0f);
    return i < 0 ? 0 : (i > GD - 1 ? GD - 1 : i);
}

// workspace section offsets (bytes), all 16B aligned
#define WS_PTS4   0          // pts4:    2*16384*16    =   524,288
#define WS_FEAT   524288     // feat_nc: 2*16384*64*2  = 4,194,304
#define WS_W1T    4718592    // 64*96*2   = 12,288
#define WS_W2T    4730880    // 64*64*2   =  8,192
#define WS_W3T    4739072    // 128*64*2  = 16,384
#define WS_SPTS   4755456    // sorted pts float4: 524,288
#define WS_SSID   5279744    // sorted orig idx:   131,072
#define WS_CELLS  5410816    // per-point cell id ushort: 2*16384*2 = 65,536
#define WS_OFF    5476352    // offsets: 2*13828*4 = 110,624
#define WS_CURS   5586976    // cursors: 2*13824*4 = 110,592 (end 5,697,568)

// prep index ranges
#define T_PTS   (BB * NN)                  // 32768
#define T_W1    (T_PTS + 64 * 96)          // 38912
#define T_W2    (T_W1 + 64 * 64)           // 43008
#define T_W3    (T_W2 + 128 * 64)          // 51200
#define T_NXYZ  (T_W3 + BB * SS * 3)       // 75776
#define T_SIDX  (T_NXYZ + BB * SS)         // 83968
#define T_ALL   (T_SIDX + BB * NN * 8)     // 346112 (feat threads, 8x split)

#define CH 54                              // cells per scan thread (256*54 == GC)

// ---------------------------------------------------------------------------
// ONE cooperative kernel for everything except samp_idx (outputs 0 and 1
// verified correct under this structure in R3/R4). samp_idx writes from
// inside the cooperative kernel mysteriously never land (two independent
// sites, both zero) — so samp_idx is delegated to a separate plain kernel
// below, using the exact store pattern that passed in R0-R2.
// Phases separated by grid.sync():
//   A: prep (wide)  B: hist+scan (blocks 0/1, packed 16-bit LDS histogram)
//   C: counting-sort scatter (wide, global atomic cursors)
//   D: fused ball-query + MLP (2 tiles/block)
// ---------------------------------------------------------------------------
__global__ __launch_bounds__(256, 4) void mega_kernel(
        const float* __restrict__ xyz, const float* __restrict__ feat,
        const float* __restrict__ W1, const float* __restrict__ b1,
        const float* __restrict__ W2, const float* __restrict__ b2,
        const float* __restrict__ W3, const float* __restrict__ b3,
        char* __restrict__ ws, float* __restrict__ out) {
    cg::grid_group gg = cg::this_grid();

    // derived sections
    float4* pts4    = (float4*)(ws + WS_PTS4);
    ushort* feat_nc = (ushort*)(ws + WS_FEAT);
    ushort* W1t     = (ushort*)(ws + WS_W1T);
    ushort* W2t     = (ushort*)(ws + WS_W2T);
    ushort* W3t     = (ushort*)(ws + WS_W3T);
    float4* spts    = (float4*)(ws + WS_SPTS);
    int*    ssid    = (int*)(ws + WS_SSID);
    ushort* cells   = (ushort*)(ws + WS_CELLS);
    uint*   offs    = (uint*)(ws + WS_OFF);
    uint*   curs    = (uint*)(ws + WS_CURS);

    float* out_xyz  = out;                               // [2,4096,3]
    float* out_feat = out + (size_t)BB * SS * 3;         // [2,128,4096]

    // one 29184B arena, reused across phases
    __shared__ __align__(16) unsigned char smem[29184];

    // ===================== phase A: prep (grid-stride) =====================
    for (int t = blockIdx.x * 256 + threadIdx.x; t < T_ALL; t += GRID * 256) {
        if (t < T_PTS) {
            const float* p = xyz + (size_t)t * 3;
            const float x = p[0], y = p[1], z = p[2];
            pts4[t] = make_float4(x, y, z, x * x + y * y + z * z);
            cells[t] = (ushort)((cellc(z) * GD + cellc(y)) * GD + cellc(x));
        } else if (t < T_W1) {
            const int i = t - T_PTS;
            const int n = i / 96, k = i - n * 96;
            float v = 0.0f;
            if (k < 64) v = W1[(3 + k) * 64 + n];
            else if (k < 67) v = W1[(k - 64) * 64 + n];
            W1t[n * 96 + k] = f2bf(v);
        } else if (t < T_W2) {
            const int i = t - T_W1;
            const int n = i >> 6, k = i & 63;
            W2t[n * 64 + k] = f2bf(W2[k * 64 + n]);
        } else if (t < T_W3) {
            const int i = t - T_W2;
            const int n = i >> 6, k = i & 63;
            W3t[n * 64 + k] = f2bf(W3[k * 128 + n]);
        } else if (t < T_NXYZ) {
            const int i = t - T_W3;              // new_xyz = xyz[:, :SS] copy
            const int b = i / (SS * 3), j = i - b * (SS * 3);
            out_xyz[i] = xyz[(size_t)b * NN * 3 + j];
        } else if (t < T_SIDX) {
            // samp_idx handled by sidx_kernel (see header comment)
        } else {
            const int j = t - T_SIDX;            // 0 .. BB*NN*8-1
            const int nl = j >> 3, c8 = j & 7;   // nl: linear point, c8: chan oct
            const int b = nl >> 14, n = nl & (NN - 1);
            const float* fb = feat + (size_t)b * CC * NN + n;
            uint u[4];
            #pragma unroll
            for (int q = 0; q < 4; ++q) {
                const float f0 = fb[(size_t)(c8 * 8 + 2 * q) * NN];
                const float f1 = fb[(size_t)(c8 * 8 + 2 * q + 1) * NN];
                u[q] = (uint)f2bf(f0) | ((uint)f2bf(f1) << 16);
            }
            *(uint4*)(feat_nc + (size_t)nl * 64 + c8 * 8) =
                make_uint4(u[0], u[1], u[2], u[3]);
        }
    }
    gg.sync();

    // ============ phase B: histogram + scan (blocks 0/1 only) ==============
    // packed histogram: two 16-bit cell counts per uint (count <= 16384 < 2^16
    // so cross-field carry is impossible). 27648B <= 29184B arena.
    if (blockIdx.x < BB) {
        uint* hist = (uint*)smem;                     // GC/2 = 6912 uints
        uint* wsum = (uint*)(smem + GC * 2);          // 4 wave sums
        const int b = blockIdx.x, t = threadIdx.x;
        const int lane = t & 63, wid = t >> 6;
        for (int i = t; i < GC / 2; i += 256) hist[i] = 0u;
        __syncthreads();
        const ushort* cb = cells + (size_t)b * NN;
        for (int i = t; i < NN; i += 256) {
            const uint c = cb[i];
            atomicAdd(&hist[c >> 1], 1u << ((c & 1) << 4));
        }
        __syncthreads();
        uint s = 0;
        for (int j = 0; j < CH; ++j) {
            const int ci = t * CH + j;
            s += (hist[ci >> 1] >> ((ci & 1) << 4)) & 0xffffu;
        }
        uint inc = s;
        #pragma unroll
        for (int o = 1; o < 64; o <<= 1) {
            const uint u = __shfl_up(inc, o);
            if (lane >= o) inc += u;
        }
        if (lane == 63) wsum[wid] = inc;
        __syncthreads();
        if (t == 0) {
            uint r = 0;
            #pragma unroll
            for (int k = 0; k < 4; ++k) { const uint v = wsum[k]; wsum[k] = r; r += v; }
        }
        __syncthreads();
        uint run = wsum[wid] + inc - s;               // exclusive prefix
        uint* offb = offs + (size_t)b * GCP;
        uint* cub  = curs + (size_t)b * GC;
        for (int j = 0; j < CH; ++j) {
            const int ci = t * CH + j;
            const uint cv = (hist[ci >> 1] >> ((ci & 1) << 4)) & 0xffffu;
            offb[ci] = run; cub[ci] = run; run += cv;
        }
        if (t == 255) offb[GC] = NN;                  // run == NN here
    }
    gg.sync();

    // ================= phase C: scatter (grid-stride, wide) ================
    // order within a cell nondeterministic — harmless: phase D selects by
    // smallest original index, a set-invariant.
    for (int i = blockIdx.x * 256 + threadIdx.x; i < BB * NN; i += GRID * 256) {
        const int b = i >> 14, n = i & (NN - 1);
        const uint cell = cells[i];
        const uint pos = atomicAdd(&curs[(size_t)b * GC + cell], 1u);
        spts[(size_t)b * NN + pos] = pts4[i];
        ssid[(size_t)b * NN + pos] = n;
    }
    gg.sync();

    // ================= phase D: fused BQ + MLP (2 tiles/block) =============
    ushort (*ldsA)[32 * 104] = (ushort(*)[32 * 104])smem;      // 26624B
    float (*stage)[5] = (float(*)[5])(smem + 26624);           // 2560B

    const int w = threadIdx.x >> 6, lane = threadIdx.x & 63;
    const int quad = lane >> 4, mrow = lane & 15;
    const int m = lane & 31, half = lane >> 5;
    ushort* gbuf = ldsA[w];
    int* hit = (int*)gbuf;                                     // 2KB bq scratch
    const unsigned long long ltmask = (1ull << lane) - 1ull;

    for (int tt = 0; tt < TILES; ++tt) {
        __syncthreads();                       // protect stage/ldsA reuse
        const int vt = tt * GRID + blockIdx.x; // 0..2047, same swizzle as before
        const int xcd = vt & 7;
        const int slot = vt >> 3;              // 0..255
        const int b = xcd >> 2;
        const int s0 = ((xcd & 3) * 256 + slot) * 4;
        const int s = s0 + w;

        const float4* pb = pts4 + (size_t)b * NN;
        const ushort* fbase = feat_nc + (size_t)b * NN * 64;

        // ---------------- ball query via grid (flattened) ----------------
        {
            const float4 c = pb[s];
            const int cx = cellc(c.x), cy = cellc(c.y), cz = cellc(c.z);
            const int x0 = cx - 1 < 0 ? 0 : cx - 1;
            const int x1 = cx + 1 > GD - 1 ? GD - 1 : cx + 1;
            const uint* off = offs + (size_t)b * GCP;
            const float4* sp = spts + (size_t)b * NN;
            const int* sidp = ssid + (size_t)b * NN;

            int rs[9], re[9], pre[10];
            pre[0] = 0;
            #pragma unroll
            for (int e = 0; e < 9; ++e) {
                const int z = cz + e / 3 - 1, y = cy + e % 3 - 1;
                const bool ok = (z >= 0) && (z < GD) && (y >= 0) && (y < GD);
                const int cbase = (z * GD + y) * GD;
                const int a = ok ? (int)off[cbase + x0] : 0;
                const int bnd = ok ? (int)off[cbase + x1 + 1] : 0;
                rs[e] = a;
                re[e] = ok ? bnd : a;
                pre[e + 1] = pre[e] + (re[e] - rs[e]);
            }
            const int tot = pre[9];

            int cnt = 0;
            for (int g0 = 0; g0 < tot; g0 += 64) {
                const int g = g0 + lane;
                int adj = rs[0];                       // pre[0] == 0
                #pragma unroll
                for (int k = 1; k < 9; ++k) adj = (g >= pre[k]) ? (rs[k] - pre[k]) : adj;
                const bool act = g < tot;
                const int idx = act ? (g + adj) : 0;
                const float4 p = sp[idx];
                const int id = sidp[idx];
                const float d = c.w + p.w - 2.0f * (c.x * p.x + c.y * p.y + c.z * p.z);
                const bool h = act && (d < R2);
                const unsigned long long mk = __ballot(h);
                if (h) {
                    const int pp = cnt + __popcll(mk & ltmask);
                    if (pp < CAP) hit[pp] = id;
                }
                cnt += (int)__popcll(mk);
            }

            // keep the 32 smallest original indices (set-equivalent to the
            // reference "first nsample in index order"; maxpool ignores order)
            if (cnt > KK) {
                const int stored = cnt < CAP ? cnt : CAP;
                int v[CAPL];
                #pragma unroll
                for (int j = 0; j < CAPL; ++j) {
                    const int q = j * 64 + lane;
                    const int val = hit[q];
                    v[j] = (q < stored) ? val : 0x7fffffff;
                }
                int lo = 0, hi = NN - 1;
                while (lo < hi) {                      // wave-uniform, <=14 iters
                    const int mid = (lo + hi) >> 1;
                    int cle = 0;
                    #pragma unroll
                    for (int j = 0; j < CAPL; ++j)
                        if (j * 64 < stored)
                            cle += (int)__popcll(__ballot(v[j] <= mid));
                    if (cle >= KK) hi = mid; else lo = mid + 1;
                }
                int pos = 0;                           // exactly KK (ids unique)
                #pragma unroll
                for (int j = 0; j < CAPL; ++j) {
                    if (j * 64 < stored) {
                        const bool sel = v[j] <= lo;
                        const unsigned long long mk = __ballot(sel);
                        if (sel) hit[pos + __popcll(mk & ltmask)] = v[j];
                        pos += (int)__popcll(mk);
                    }
                }
            } else if (lane < KK) {
                const int vv = (cnt == 0) ? 0 : ((lane < cnt) ? hit[lane] : hit[0]);
                hit[lane] = vv;
            }
        }

        // ---------------- gather: sid (LDS) -> rows -> LDS ----------------
        {
            const int sid = hit[m];
            const ushort* src = fbase + (size_t)sid * 64 + half * 32;
            ushort* dst = gbuf + m * 104 + half * 32;
            uint4 rows[4];
            #pragma unroll
            for (int i = 0; i < 4; ++i) rows[i] = *(const uint4*)(src + i * 8);
            const float4 p = pb[sid];
            const float4 cc = pb[s];
            #pragma unroll
            for (int i = 0; i < 4; ++i) *(uint4*)(dst + i * 8) = rows[i];
            if (half == 0) {
                bf16x8 rel = {(__bf16)(p.x - cc.x), (__bf16)(p.y - cc.y),
                              (__bf16)(p.z - cc.z), (__bf16)0.f,
                              (__bf16)0.f, (__bf16)0.f, (__bf16)0.f, (__bf16)0.f};
                *(bf16x8*)(gbuf + m * 104 + 64) = rel;
                *(uint4*)(gbuf + m * 104 + 88) = make_uint4(0, 0, 0, 0);
            } else {
                *(uint4*)(gbuf + m * 104 + 72) = make_uint4(0, 0, 0, 0);
                *(uint4*)(gbuf + m * 104 + 80) = make_uint4(0, 0, 0, 0);
            }
        }

        // ---------------- layer 1: [32x96]x[96x64] ----------------
        {
            f32x4 acc[2][4];
            #pragma unroll
            for (int nt = 0; nt < 4; ++nt) {
                const float bv = b1[nt * 16 + mrow];
                acc[0][nt] = (f32x4){bv, bv, bv, bv};
                acc[1][nt] = acc[0][nt];
            }
            #pragma unroll
            for (int ks = 0; ks < 3; ++ks) {
                const bf16x8 a0 = *(const bf16x8*)(gbuf + mrow * 104 + ks * 32 + quad * 8);
                const bf16x8 a1 = *(const bf16x8*)(gbuf + (16 + mrow) * 104 + ks * 32 + quad * 8);
                #pragma unroll
                for (int nt = 0; nt < 4; ++nt) {
                    const bf16x8 wf = *(const bf16x8*)(W1t + (nt * 16 + mrow) * 96 + ks * 32 + quad * 8);
                    acc[0][nt] = MFMA(a0, wf, acc[0][nt]);
                    acc[1][nt] = MFMA(a1, wf, acc[1][nt]);
                }
            }
            #pragma unroll
            for (int mt = 0; mt < 2; ++mt)
                #pragma unroll
                for (int nt = 0; nt < 4; ++nt)
                    #pragma unroll
                    for (int r = 0; r < 4; ++r)
                        gbuf[(mt * 16 + quad * 4 + r) * 104 + nt * 16 + mrow] =
                            f2bf(fmaxf(acc[mt][nt][r], 0.0f));
        }

        // ---------------- layer 2: [32x64]x[64x64] ----------------
        {
            f32x4 acc[2][4];
            #pragma unroll
            for (int nt = 0; nt < 4; ++nt) {
                const float bv = b2[nt * 16 + mrow];
                acc[0][nt] = (f32x4){bv, bv, bv, bv};
                acc[1][nt] = acc[0][nt];
            }
            #pragma unroll
            for (int ks = 0; ks < 2; ++ks) {
                const bf16x8 a0 = *(const bf16x8*)(gbuf + mrow * 104 + ks * 32 + quad * 8);
                const bf16x8 a1 = *(const bf16x8*)(gbuf + (16 + mrow) * 104 + ks * 32 + quad * 8);
                #pragma unroll
                for (int nt = 0; nt < 4; ++nt) {
                    const bf16x8 wf = *(const bf16x8*)(W2t + (nt * 16 + mrow) * 64 + ks * 32 + quad * 8);
                    acc[0][nt] = MFMA(a0, wf, acc[0][nt]);
                    acc[1][nt] = MFMA(a1, wf, acc[1][nt]);
                }
            }
            #pragma unroll
            for (int mt = 0; mt < 2; ++mt)
                #pragma unroll
                for (int nt = 0; nt < 4; ++nt)
                    #pragma unroll
                    for (int r = 0; r < 4; ++r)
                        gbuf[(mt * 16 + quad * 4 + r) * 104 + nt * 16 + mrow] =
                            f2bf(fmaxf(acc[mt][nt][r], 0.0f));
        }

        // -------- layer 3: [32x64]x[64x128] two n-halves + maxpool --------
        #pragma unroll
        for (int nh = 0; nh < 2; ++nh) {
            f32x4 acc[2][4];
            #pragma unroll
            for (int ntl = 0; ntl < 4; ++ntl) {
                const float bv = b3[(nh * 4 + ntl) * 16 + mrow];
                acc[0][ntl] = (f32x4){bv, bv, bv, bv};
                acc[1][ntl] = acc[0][ntl];
            }
            #pragma unroll
            for (int ks = 0; ks < 2; ++ks) {
                const bf16x8 a0 = *(const bf16x8*)(gbuf + mrow * 104 + ks * 32 + quad * 8);
                const bf16x8 a1 = *(const bf16x8*)(gbuf + (16 + mrow) * 104 + ks * 32 + quad * 8);
                #pragma unroll
                for (int ntl = 0; ntl < 4; ++ntl) {
                    const bf16x8 wf = *(const bf16x8*)(
                        W3t + ((nh * 4 + ntl) * 16 + mrow) * 64 + ks * 32 + quad * 8);
                    acc[0][ntl] = MFMA(a0, wf, acc[0][ntl]);
                    acc[1][ntl] = MFMA(a1, wf, acc[1][ntl]);
                }
            }
            #pragma unroll
            for (int ntl = 0; ntl < 4; ++ntl) {
                const f32x4 v0 = acc[0][ntl], v1 = acc[1][ntl];
                float mx = fmaxf(fmaxf(v0[0], v0[1]), fmaxf(v0[2], v0[3]));
                mx = fmaxf(mx, fmaxf(fmaxf(v1[0], v1[1]), fmaxf(v1[2], v1[3])));
                mx = fmaxf(mx, __shfl_xor(mx, 16));
                mx = fmaxf(mx, __shfl_xor(mx, 32));
                mx = fmaxf(mx, 0.0f);
                if (quad == 0) stage[(nh * 4 + ntl) * 16 + mrow][w] = mx;
            }
        }
        __syncthreads();

        // ---- epilogue: 128 ch x 4 s, float2 per thread ----
        {
            const int ch = threadIdx.x & 127;
            const int hf = threadIdx.x >> 7;           // 0/1
            float* dst = out_feat + ((size_t)b * 128 + ch) * SS + s0 + hf * 2;
            *(float2*)dst = make_float2(stage[ch][hf * 2], stage[ch][hf * 2 + 1]);
        }
    }
}

// ---------------------------------------------------------------------------
// samp_idx writer — plain (non-cooperative) dispatch, byte-identical store
// pattern to the R0-R2 prep branch that passed. 32 blocks.
// ---------------------------------------------------------------------------
__global__ __launch_bounds__(256) void sidx_kernel(float* __restrict__ out_sidx) {
    const int i = blockIdx.x * 256 + threadIdx.x;      // 0 .. BB*SS-1
    out_sidx[i] = (float)(i & (SS - 1));
}

// ---------------------------------------------------------------------------
extern "C" void kernel_launch(void* const* d_in, const int* in_sizes, int n_in,
                              void* d_out, int out_size, void* d_ws, size_t ws_size,
                              hipStream_t stream) {
    const float* xyz  = (const float*)d_in[0];
    const float* feat = (const float*)d_in[1];
    const float* W1   = (const float*)d_in[2];
    const float* b1   = (const float*)d_in[3];
    const float* W2   = (const float*)d_in[4];
    const float* b2   = (const float*)d_in[5];
    const float* W3   = (const float*)d_in[6];
    const float* b3   = (const float*)d_in[7];

    char*  ws  = (char*)d_ws;
    float* out = (float*)d_out;
    float* out_sidx = out + (size_t)BB * SS * 3 + (size_t)BB * 128 * SS;

    void* args[] = {
        (void*)&xyz, (void*)&feat,
        (void*)&W1, (void*)&b1, (void*)&W2, (void*)&b2, (void*)&W3, (void*)&b3,
        (void*)&ws, (void*)&out
    };
    hipLaunchCooperativeKernel(reinterpret_cast<void*>(mega_kernel),
                               dim3(GRID), dim3(256), args, 0, stream);
    sidx_kernel<<<BB * SS / 256, 256, 0, stream>>>(out_sidx);
}

// Round 6
// 148.478 us; speedup vs baseline: 3.5541x; 3.5541x over previous
//
#include <hip/hip_runtime.h>

#define BB 2
#define NN 16384
#define CC 64
#define SS 4096
#define KK 32
#define R2 0.16f   // RADIUS^2

// spatial grid: cell = RADIUS, 24^3 cells covering [-4.8, 4.8] (clamped; the
// clamp is monotone so the 3x3x3 neighborhood remains a superset of the ball
// for ANY input magnitude — tail points just pile into edge cells)
#define GD   24
#define GC   (GD * GD * GD)       // 13824 cells per batch
#define CAPC 112                  // per-cell bucket capacity (center cell ~62)
#define CAP  512                  // per-wave hit-list capacity (max expected ~360)
#define CAPL (CAP / 64)           // 8 register chunks for selection

typedef __bf16 bf16x8 __attribute__((ext_vector_type(8)));
typedef float  f32x4  __attribute__((ext_vector_type(4)));

#define MFMA(a, b, c) __builtin_amdgcn_mfma_f32_16x16x32_bf16((a), (b), (c), 0, 0, 0)

static __device__ __forceinline__ ushort f2bf(float f) {
    __bf16 h = (__bf16)f;
    return *(ushort*)&h;
}

static __device__ __forceinline__ int cellc(float x) {
    int i = (int)floorf(x * 2.5f + 12.0f);
    return i < 0 ? 0 : (i > GD - 1 ? GD - 1 : i);
}

// workspace section offsets (bytes), all 16B aligned
#define WS_PTS4   0          // pts4:    2*16384*16    =   524,288
#define WS_FEAT   524288     // feat_nc: 2*16384*64*2  = 4,194,304
#define WS_W1T    4718592    // 64*96*2   = 12,288
#define WS_W2T    4730880    // 64*64*2   =  8,192
#define WS_W3T    4739072    // 128*64*2  = 16,384
#define WS_CNT    4755456    // counts: 2*13824*4 = 110,592
#define WS_LIST   4866048    // lists: 2*13824*112*4 = 12,386,304 (end 17,252,352)

// prep index ranges
#define T_PTS   (BB * NN)                  // 32768
#define T_W1    (T_PTS + 64 * 96)          // 38912
#define T_W2    (T_W1 + 64 * 64)           // 43008
#define T_W3    (T_W2 + 128 * 64)          // 51200
#define T_NXYZ  (T_W3 + BB * SS * 3)       // 75776
#define T_SIDX  (T_NXYZ + BB * SS)         // 83968
#define T_ALL   (T_SIDX + BB * NN * 8)     // 346112 (feat threads, 8x split)

// ---------------------------------------------------------------------------
// prep: pts4=(x,y,z,|x|^2) + direct per-cell bucket insert (replaces the
// entire histogram/scan/scatter stage — that machinery measured ~75-95us);
// bf16 weight transposes; coalesced new_xyz copy; samp_idx; feat [B][C][N]
// fp32 -> [B][N][C] bf16 (8 threads/point). One wide launch.
// ---------------------------------------------------------------------------
__global__ __launch_bounds__(256) void prep_kernel(
        const float* __restrict__ xyz, const float* __restrict__ feat,
        const float* __restrict__ W1, const float* __restrict__ W2,
        const float* __restrict__ W3,
        float4* __restrict__ pts4, ushort* __restrict__ feat_nc,
        ushort* __restrict__ W1t, ushort* __restrict__ W2t,
        ushort* __restrict__ W3t,
        float* __restrict__ out_xyz, float* __restrict__ out_sidx,
        uint* __restrict__ counts, int* __restrict__ list) {
    const int t = blockIdx.x * 256 + threadIdx.x;
    if (t < T_PTS) {
        const float* p = xyz + (size_t)t * 3;
        const float x = p[0], y = p[1], z = p[2];
        pts4[t] = make_float4(x, y, z, x * x + y * y + z * z);
        const int cell = (cellc(z) * GD + cellc(y)) * GD + cellc(x);
        const int b = t >> 14, n = t & (NN - 1);
        const uint rank = atomicAdd(&counts[(size_t)b * GC + cell], 1u);
        if (rank < CAPC)
            list[((size_t)b * GC + cell) * CAPC + rank] = n;
    } else if (t < T_W1) {
        const int i = t - T_PTS;
        const int n = i / 96, k = i - n * 96;
        float v = 0.0f;
        if (k < 64) v = W1[(3 + k) * 64 + n];
        else if (k < 67) v = W1[(k - 64) * 64 + n];
        W1t[n * 96 + k] = f2bf(v);
    } else if (t < T_W2) {
        const int i = t - T_W1;
        const int n = i >> 6, k = i & 63;
        W2t[n * 64 + k] = f2bf(W2[k * 64 + n]);
    } else if (t < T_W3) {
        const int i = t - T_W2;
        const int n = i >> 6, k = i & 63;
        W3t[n * 64 + k] = f2bf(W3[k * 128 + n]);
    } else if (t < T_NXYZ) {
        const int i = t - T_W3;              // new_xyz = xyz[:, :SS] copy
        const int b = i / (SS * 3), j = i - b * (SS * 3);
        out_xyz[i] = xyz[(size_t)b * NN * 3 + j];
    } else if (t < T_SIDX) {
        const int i = t - T_NXYZ;
        out_sidx[i] = (float)(i & (SS - 1));
    } else if (t < T_ALL) {
        const int j = t - T_SIDX;            // 0 .. BB*NN*8-1
        const int nl = j >> 3, c8 = j & 7;   // nl: linear point, c8: channel oct
        const int b = nl >> 14, n = nl & (NN - 1);
        const float* fb = feat + (size_t)b * CC * NN + n;
        uint u[4];
        #pragma unroll
        for (int q = 0; q < 4; ++q) {
            const float f0 = fb[(size_t)(c8 * 8 + 2 * q) * NN];
            const float f1 = fb[(size_t)(c8 * 8 + 2 * q + 1) * NN];
            u[q] = (uint)f2bf(f0) | ((uint)f2bf(f1) << 16);
        }
        *(uint4*)(feat_nc + (size_t)nl * 64 + c8 * 8) = make_uint4(u[0], u[1], u[2], u[3]);
    }
}

// ---------------------------------------------------------------------------
// fused: one wave = one centroid. Ball query over the 27 neighbor-cell bucket
// lists, flattened: 27 counts loaded up front, register prefix table (fully
// unrolled, constant-indexed), one dense loop over the candidate union
// (list -> id -> pts4 gather, both L2-resident). Selection of the 32 smallest
// ids via binary search with ballot-popcount counting. Then gather + 3-layer
// MLP + maxpool — byte-identical to the R2 kernel that passed at 57.5us.
// ---------------------------------------------------------------------------
__global__ __launch_bounds__(256, 2) void fused_kernel(
        const float4* __restrict__ pts4, const ushort* __restrict__ feat_nc,
        const uint* __restrict__ counts, const int* __restrict__ list,
        const ushort* __restrict__ W1t, const ushort* __restrict__ W2t,
        const ushort* __restrict__ W3t,
        const float* __restrict__ b1, const float* __restrict__ b2,
        const float* __restrict__ b3, float* __restrict__ out_feat) {
    const int w = threadIdx.x >> 6, lane = threadIdx.x & 63;
    const int quad = lane >> 4, mrow = lane & 15;
    const int m = lane & 31, half = lane >> 5;

    __shared__ __align__(16) ushort ldsA[4][32 * 104];   // hits -> g -> h1 -> h2
    __shared__ float stage[128][5];                      // [ch][4 s + pad]
    ushort* gbuf = ldsA[w];
    int* hit = (int*)gbuf;                               // 2KB bq scratch (CAP ints)

    const int xcd = blockIdx.x & 7;
    const int slot = blockIdx.x >> 3;              // 0..255
    const int b = xcd >> 2;
    const int s0 = ((xcd & 3) * 256 + slot) * 4;   // block's 4-s tile
    const int s = s0 + w;

    const float4* pb = pts4 + (size_t)b * NN;
    const ushort* fbase = feat_nc + (size_t)b * NN * 64;
    const unsigned long long ltmask = (1ull << lane) - 1ull;

    // ================= ball query via cell bucket lists =================
    {
        const float4 c = pb[s];
        const int cx = cellc(c.x), cy = cellc(c.y), cz = cellc(c.z);
        const uint* cntb = counts + (size_t)b * GC;
        const int* listb = list + (size_t)b * GC * CAPC;

        // 27-cell register prefix table (all constant-indexed: rule-#20 safe)
        int pre[28], A[27];
        pre[0] = 0;
        #pragma unroll
        for (int e = 0; e < 27; ++e) {
            const int z = cz + e / 9 - 1;
            const int y = cy + (e / 3) % 3 - 1;
            const int x = cx + e % 3 - 1;
            const bool ok = ((unsigned)z < GD) && ((unsigned)y < GD) && ((unsigned)x < GD);
            const int ci = (z * GD + y) * GD + x;
            int cn = ok ? (int)cntb[ci] : 0;
            cn = cn < CAPC ? cn : CAPC;          // overflow clamp (memory safety)
            A[e] = ci * CAPC - pre[e];
            pre[e + 1] = pre[e] + cn;
        }
        const int tot = pre[27];

        int cnt = 0;
        for (int g0 = 0; g0 < tot; g0 += 64) {
            const int g = g0 + lane;
            int adj = A[0];
            #pragma unroll
            for (int k = 1; k < 27; ++k) adj = (g >= pre[k]) ? A[k] : adj;
            const bool act = g < tot;
            const int id = act ? listb[g + adj] : 0;
            const float4 p = pb[id];
            const float d = c.w + p.w - 2.0f * (c.x * p.x + c.y * p.y + c.z * p.z);
            const bool h = act && (d < R2);
            const unsigned long long mk = __ballot(h);
            if (h) {
                const int pp = cnt + __popcll(mk & ltmask);
                if (pp < CAP) hit[pp] = id;
            }
            cnt += (int)__popcll(mk);
        }

        // ---- keep the 32 smallest original indices (set-equivalent to the
        // reference "first nsample in index order"; maxpool ignores order) ----
        if (cnt > KK) {
            const int stored = cnt < CAP ? cnt : CAP;
            int v[CAPL];
            #pragma unroll
            for (int j = 0; j < CAPL; ++j) {
                const int q = j * 64 + lane;
                const int val = hit[q];            // within allocated LDS
                v[j] = (q < stored) ? val : 0x7fffffff;
            }
            int lo = 0, hi = NN - 1;
            while (lo < hi) {                      // wave-uniform, <=14 iters
                const int mid = (lo + hi) >> 1;
                int cle = 0;
                #pragma unroll
                for (int j = 0; j < CAPL; ++j)
                    if (j * 64 < stored)           // wave-uniform chunk gate
                        cle += (int)__popcll(__ballot(v[j] <= mid));
                if (cle >= KK) hi = mid; else lo = mid + 1;
            }
            int pos = 0;                           // exactly KK selected (ids unique)
            #pragma unroll
            for (int j = 0; j < CAPL; ++j) {
                if (j * 64 < stored) {
                    const bool sel = v[j] <= lo;
                    const unsigned long long mk = __ballot(sel);
                    if (sel) hit[pos + __popcll(mk & ltmask)] = v[j];
                    pos += (int)__popcll(mk);
                }
            }
        } else if (lane < KK) {
            const int vv = (cnt == 0) ? 0 : ((lane < cnt) ? hit[lane] : hit[0]);
            hit[lane] = vv;
        }
    }

    // ================= gather: sid (LDS) -> rows -> LDS =================
    {
        const int sid = hit[m];                  // wave-private, program order
        const ushort* src = fbase + (size_t)sid * 64 + half * 32;
        ushort* dst = gbuf + m * 104 + half * 32;
        uint4 rows[4];
        #pragma unroll
        for (int i = 0; i < 4; ++i) rows[i] = *(const uint4*)(src + i * 8);
        const float4 p = pb[sid];
        const float4 cc = pb[s];
        #pragma unroll
        for (int i = 0; i < 4; ++i) *(uint4*)(dst + i * 8) = rows[i];
        if (half == 0) {
            bf16x8 rel = {(__bf16)(p.x - cc.x), (__bf16)(p.y - cc.y),
                          (__bf16)(p.z - cc.z), (__bf16)0.f,
                          (__bf16)0.f, (__bf16)0.f, (__bf16)0.f, (__bf16)0.f};
            *(bf16x8*)(gbuf + m * 104 + 64) = rel;
            *(uint4*)(gbuf + m * 104 + 88) = make_uint4(0, 0, 0, 0);
        } else {
            *(uint4*)(gbuf + m * 104 + 72) = make_uint4(0, 0, 0, 0);
            *(uint4*)(gbuf + m * 104 + 80) = make_uint4(0, 0, 0, 0);
        }
    }

    // ================= layer 1: [32x96]x[96x64] =================
    {
        f32x4 acc[2][4];
        #pragma unroll
        for (int nt = 0; nt < 4; ++nt) {
            const float bv = b1[nt * 16 + mrow];
            acc[0][nt] = (f32x4){bv, bv, bv, bv};
            acc[1][nt] = acc[0][nt];
        }
        #pragma unroll
        for (int ks = 0; ks < 3; ++ks) {
            const bf16x8 a0 = *(const bf16x8*)(gbuf + mrow * 104 + ks * 32 + quad * 8);
            const bf16x8 a1 = *(const bf16x8*)(gbuf + (16 + mrow) * 104 + ks * 32 + quad * 8);
            #pragma unroll
            for (int nt = 0; nt < 4; ++nt) {
                const bf16x8 wf = *(const bf16x8*)(W1t + (nt * 16 + mrow) * 96 + ks * 32 + quad * 8);
                acc[0][nt] = MFMA(a0, wf, acc[0][nt]);
                acc[1][nt] = MFMA(a1, wf, acc[1][nt]);
            }
        }
        #pragma unroll
        for (int mt = 0; mt < 2; ++mt)
            #pragma unroll
            for (int nt = 0; nt < 4; ++nt)
                #pragma unroll
                for (int r = 0; r < 4; ++r)
                    gbuf[(mt * 16 + quad * 4 + r) * 104 + nt * 16 + mrow] =
                        f2bf(fmaxf(acc[mt][nt][r], 0.0f));
    }

    // ================= layer 2: [32x64]x[64x64] =================
    {
        f32x4 acc[2][4];
        #pragma unroll
        for (int nt = 0; nt < 4; ++nt) {
            const float bv = b2[nt * 16 + mrow];
            acc[0][nt] = (f32x4){bv, bv, bv, bv};
            acc[1][nt] = acc[0][nt];
        }
        #pragma unroll
        for (int ks = 0; ks < 2; ++ks) {
            const bf16x8 a0 = *(const bf16x8*)(gbuf + mrow * 104 + ks * 32 + quad * 8);
            const bf16x8 a1 = *(const bf16x8*)(gbuf + (16 + mrow) * 104 + ks * 32 + quad * 8);
            #pragma unroll
            for (int nt = 0; nt < 4; ++nt) {
                const bf16x8 wf = *(const bf16x8*)(W2t + (nt * 16 + mrow) * 64 + ks * 32 + quad * 8);
                acc[0][nt] = MFMA(a0, wf, acc[0][nt]);
                acc[1][nt] = MFMA(a1, wf, acc[1][nt]);
            }
        }
        #pragma unroll
        for (int mt = 0; mt < 2; ++mt)
            #pragma unroll
            for (int nt = 0; nt < 4; ++nt)
                #pragma unroll
                for (int r = 0; r < 4; ++r)
                    gbuf[(mt * 16 + quad * 4 + r) * 104 + nt * 16 + mrow] =
                        f2bf(fmaxf(acc[mt][nt][r], 0.0f));
    }

    // ============ layer 3: [32x64]x[64x128] two n-halves + maxpool ==========
    #pragma unroll
    for (int nh = 0; nh < 2; ++nh) {
        f32x4 acc[2][4];
        #pragma unroll
        for (int ntl = 0; ntl < 4; ++ntl) {
            const float bv = b3[(nh * 4 + ntl) * 16 + mrow];
            acc[0][ntl] = (f32x4){bv, bv, bv, bv};
            acc[1][ntl] = acc[0][ntl];
        }
        #pragma unroll
        for (int ks = 0; ks < 2; ++ks) {
            const bf16x8 a0 = *(const bf16x8*)(gbuf + mrow * 104 + ks * 32 + quad * 8);
            const bf16x8 a1 = *(const bf16x8*)(gbuf + (16 + mrow) * 104 + ks * 32 + quad * 8);
            #pragma unroll
            for (int ntl = 0; ntl < 4; ++ntl) {
                const bf16x8 wf = *(const bf16x8*)(
                    W3t + ((nh * 4 + ntl) * 16 + mrow) * 64 + ks * 32 + quad * 8);
                acc[0][ntl] = MFMA(a0, wf, acc[0][ntl]);
                acc[1][ntl] = MFMA(a1, wf, acc[1][ntl]);
            }
        }
        #pragma unroll
        for (int ntl = 0; ntl < 4; ++ntl) {
            const f32x4 v0 = acc[0][ntl], v1 = acc[1][ntl];
            float mx = fmaxf(fmaxf(v0[0], v0[1]), fmaxf(v0[2], v0[3]));
            mx = fmaxf(mx, fmaxf(fmaxf(v1[0], v1[1]), fmaxf(v1[2], v1[3])));
            mx = fmaxf(mx, __shfl_xor(mx, 16));
            mx = fmaxf(mx, __shfl_xor(mx, 32));
            mx = fmaxf(mx, 0.0f);
            if (quad == 0) stage[(nh * 4 + ntl) * 16 + mrow][w] = mx;
        }
    }
    __syncthreads();

    // ---- epilogue: 128 ch x 4 s, float2 per thread -------------------------
    {
        const int ch = threadIdx.x & 127;
        const int hf = threadIdx.x >> 7;           // 0/1
        float* dst = out_feat + ((size_t)b * 128 + ch) * SS + s0 + hf * 2;
        *(float2*)dst = make_float2(stage[ch][hf * 2], stage[ch][hf * 2 + 1]);
    }
}

// ---------------------------------------------------------------------------
extern "C" void kernel_launch(void* const* d_in, const int* in_sizes, int n_in,
                              void* d_out, int out_size, void* d_ws, size_t ws_size,
                              hipStream_t stream) {
    const float* xyz  = (const float*)d_in[0];
    const float* feat = (const float*)d_in[1];
    const float* W1   = (const float*)d_in[2];
    const float* b1   = (const float*)d_in[3];
    const float* W2   = (const float*)d_in[4];
    const float* b2   = (const float*)d_in[5];
    const float* W3   = (const float*)d_in[6];
    const float* b3   = (const float*)d_in[7];

    float* out      = (float*)d_out;
    float* out_xyz  = out;                               // [2,4096,3]
    float* out_feat = out + (size_t)BB * SS * 3;         // [2,128,4096]
    float* out_sidx = out_feat + (size_t)BB * 128 * SS;  // [2,4096]

    char* ws = (char*)d_ws;
    float4* pts4    = (float4*)(ws + WS_PTS4);
    ushort* feat_nc = (ushort*)(ws + WS_FEAT);
    ushort* W1t     = (ushort*)(ws + WS_W1T);
    ushort* W2t     = (ushort*)(ws + WS_W2T);
    ushort* W3t     = (ushort*)(ws + WS_W3T);
    uint*   counts  = (uint*)(ws + WS_CNT);
    int*    list    = (int*)(ws + WS_LIST);

    hipMemsetAsync(counts, 0, (size_t)BB * GC * 4, stream);
    prep_kernel<<<(T_ALL + 255) / 256, 256, 0, stream>>>(
        xyz, feat, W1, W2, W3, pts4, feat_nc, W1t, W2t, W3t, out_xyz, out_sidx,
        counts, list);
    fused_kernel<<<BB * SS / 4, 256, 0, stream>>>(pts4, feat_nc, counts, list,
                                                  W1t, W2t, W3t, b1, b2, b3,
                                                  out_feat);
}

// Round 7
// 144.585 us; speedup vs baseline: 3.6498x; 1.0269x over previous
//
#include <hip/hip_runtime.h>

#define BB 2
#define NN 16384
#define CC 64
#define SS 4096
#define KK 32
#define R2 0.16f   // RADIUS^2

// spatial grid: cell = RADIUS, 24^3 cells covering [-4.8, 4.8] (clamped; the
// clamp is monotone so the 3x3x3 neighborhood remains a superset of the ball
// for ANY input magnitude — tail points just pile into edge cells)
#define GD   24
#define GC   (GD * GD * GD)       // 13824 cells per batch
#define CAPC 112                  // per-cell bucket capacity (center cell ~66)
#define CAP  512                  // per-wave hit-list capacity (max expected ~360)
#define CAPL (CAP / 64)           // 8 register chunks for selection

typedef __bf16 bf16x8 __attribute__((ext_vector_type(8)));
typedef float  f32x4  __attribute__((ext_vector_type(4)));

#define MFMA(a, b, c) __builtin_amdgcn_mfma_f32_16x16x32_bf16((a), (b), (c), 0, 0, 0)

static __device__ __forceinline__ ushort f2bf(float f) {
    __bf16 h = (__bf16)f;
    return *(ushort*)&h;
}

static __device__ __forceinline__ int cellc(float x) {
    int i = (int)floorf(x * 2.5f + 12.0f);
    return i < 0 ? 0 : (i > GD - 1 ? GD - 1 : i);
}

// workspace section offsets (bytes), all 16B aligned
#define WS_PTS4   0          // pts4:    2*16384*16    =   524,288
#define WS_FEAT   524288     // feat_nc: 2*16384*64*2  = 4,194,304
#define WS_W1T    4718592    // 64*96*2   = 12,288
#define WS_W2T    4730880    // 64*64*2   =  8,192
#define WS_W3T    4739072    // 128*64*2  = 16,384
#define WS_CNT    4755456    // counts: 2*13824*4 = 110,592
#define WS_LIST   4866048    // id lists: 2*13824*112*4 = 12,386,304
#define WS_LPTS   17252352   // coord buckets: 2*13824*112*16 = 49,545,216
                             // (end 66,797,568)

// prep index ranges (block-granular: T_SIDX = 328 blocks exactly)
#define T_PTS   (BB * NN)                  // 32768
#define T_W1    (T_PTS + 64 * 96)          // 38912
#define T_W2    (T_W1 + 64 * 64)           // 43008
#define T_W3    (T_W2 + 128 * 64)          // 51200
#define T_NXYZ  (T_W3 + BB * SS * 3)       // 75776
#define T_SIDX  (T_NXYZ + BB * SS)         // 83968 = 328*256
#define FEAT_B0 (T_SIDX / 256)             // 328: first feat-transpose block
#define NBLK    (FEAT_B0 + BB * (NN / 32)) // 328 + 1024 = 1352 blocks

// ---------------------------------------------------------------------------
// prep: pts4=(x,y,z,|x|^2) + coordinate-carrying per-cell bucket insert
// (bucket entries stream coalesced in the fused BQ — removes R6's random
// pts4[id] gather, the measured 14us fused regression vs R2); bf16 weight
// transposes; coalesced new_xyz copy; samp_idx; feat [B][C][N] fp32 ->
// [B][N][C] bf16 via LDS-tiled transpose (blocks >= FEAT_B0, fully
// coalesced reads AND writes). One wide launch.
// ---------------------------------------------------------------------------
__global__ __launch_bounds__(256) void prep_kernel(
        const float* __restrict__ xyz, const float* __restrict__ feat,
        const float* __restrict__ W1, const float* __restrict__ W2,
        const float* __restrict__ W3,
        float4* __restrict__ pts4, ushort* __restrict__ feat_nc,
        ushort* __restrict__ W1t, ushort* __restrict__ W2t,
        ushort* __restrict__ W3t,
        float* __restrict__ out_xyz, float* __restrict__ out_sidx,
        uint* __restrict__ counts, int* __restrict__ list,
        float4* __restrict__ lpts) {
    if (blockIdx.x >= FEAT_B0) {
        // ---- LDS-tiled feat transpose: one 64ch x 32pt tile per block ----
        __shared__ float tile[64][33];                 // +1 pad
        const int g = blockIdx.x - FEAT_B0;            // 0..1023
        const int b = g >> 9, n0 = (g & 511) << 5;
        const int t = threadIdx.x;
        const float* fb = feat + (size_t)b * CC * NN + n0;
        #pragma unroll
        for (int cc = 0; cc < 8; ++cc) {
            const int c = cc * 8 + (t >> 5);
            tile[c][t & 31] = fb[(size_t)c * NN + (t & 31)];
        }
        __syncthreads();
        const int p = t >> 3, c8 = t & 7;
        uint u[4];
        #pragma unroll
        for (int q = 0; q < 4; ++q) {
            u[q] = (uint)f2bf(tile[c8 * 8 + 2 * q][p]) |
                   ((uint)f2bf(tile[c8 * 8 + 2 * q + 1][p]) << 16);
        }
        *(uint4*)(feat_nc + ((size_t)b * NN + n0 + p) * 64 + c8 * 8) =
            make_uint4(u[0], u[1], u[2], u[3]);
        return;
    }
    const int t = blockIdx.x * 256 + threadIdx.x;
    if (t < T_PTS) {
        const float* p = xyz + (size_t)t * 3;
        const float x = p[0], y = p[1], z = p[2];
        const float4 pv = make_float4(x, y, z, x * x + y * y + z * z);
        pts4[t] = pv;
        const int cell = (cellc(z) * GD + cellc(y)) * GD + cellc(x);
        const int b = t >> 14, n = t & (NN - 1);
        const uint rank = atomicAdd(&counts[(size_t)b * GC + cell], 1u);
        if (rank < CAPC) {
            const size_t slot = ((size_t)b * GC + cell) * CAPC + rank;
            list[slot] = n;
            lpts[slot] = pv;
        }
    } else if (t < T_W1) {
        const int i = t - T_PTS;
        const int n = i / 96, k = i - n * 96;
        float v = 0.0f;
        if (k < 64) v = W1[(3 + k) * 64 + n];
        else if (k < 67) v = W1[(k - 64) * 64 + n];
        W1t[n * 96 + k] = f2bf(v);
    } else if (t < T_W2) {
        const int i = t - T_W1;
        const int n = i >> 6, k = i & 63;
        W2t[n * 64 + k] = f2bf(W2[k * 64 + n]);
    } else if (t < T_W3) {
        const int i = t - T_W2;
        const int n = i >> 6, k = i & 63;
        W3t[n * 64 + k] = f2bf(W3[k * 128 + n]);
    } else if (t < T_NXYZ) {
        const int i = t - T_W3;              // new_xyz = xyz[:, :SS] copy
        const int b = i / (SS * 3), j = i - b * (SS * 3);
        out_xyz[i] = xyz[(size_t)b * NN * 3 + j];
    } else if (t < T_SIDX) {
        const int i = t - T_NXYZ;
        out_sidx[i] = (float)(i & (SS - 1));
    }
}

// ---------------------------------------------------------------------------
// fused: one wave = one centroid. Ball query over the 27 neighbor-cell bucket
// lists, flattened: 27 counts loaded up front, register prefix table (fully
// unrolled, constant-indexed), one dense loop streaming coordinate-carrying
// bucket entries (coalesced float4; id read only for hit lanes). Selection of
// the 32 smallest ids via binary search with ballot-popcount counting. Then
// gather + 3-layer MLP + maxpool — byte-identical to R2/R6.
// ---------------------------------------------------------------------------
__global__ __launch_bounds__(256, 2) void fused_kernel(
        const float4* __restrict__ pts4, const ushort* __restrict__ feat_nc,
        const uint* __restrict__ counts, const int* __restrict__ list,
        const float4* __restrict__ lpts,
        const ushort* __restrict__ W1t, const ushort* __restrict__ W2t,
        const ushort* __restrict__ W3t,
        const float* __restrict__ b1, const float* __restrict__ b2,
        const float* __restrict__ b3, float* __restrict__ out_feat) {
    const int w = threadIdx.x >> 6, lane = threadIdx.x & 63;
    const int quad = lane >> 4, mrow = lane & 15;
    const int m = lane & 31, half = lane >> 5;

    __shared__ __align__(16) ushort ldsA[4][32 * 104];   // hits -> g -> h1 -> h2
    __shared__ float stage[128][5];                      // [ch][4 s + pad]
    ushort* gbuf = ldsA[w];
    int* hit = (int*)gbuf;                               // 2KB bq scratch (CAP ints)

    const int xcd = blockIdx.x & 7;
    const int slot = blockIdx.x >> 3;              // 0..255
    const int b = xcd >> 2;
    const int s0 = ((xcd & 3) * 256 + slot) * 4;   // block's 4-s tile
    const int s = s0 + w;

    const float4* pb = pts4 + (size_t)b * NN;
    const ushort* fbase = feat_nc + (size_t)b * NN * 64;
    const unsigned long long ltmask = (1ull << lane) - 1ull;

    // ================= ball query via cell bucket lists =================
    {
        const float4 c = pb[s];
        const int cx = cellc(c.x), cy = cellc(c.y), cz = cellc(c.z);
        const uint* cntb = counts + (size_t)b * GC;
        const int* listb = list + (size_t)b * GC * CAPC;
        const float4* lptsb = lpts + (size_t)b * GC * CAPC;

        // 27-cell register prefix table (all constant-indexed: rule-#20 safe)
        int pre[28], A[27];
        pre[0] = 0;
        #pragma unroll
        for (int e = 0; e < 27; ++e) {
            const int z = cz + e / 9 - 1;
            const int y = cy + (e / 3) % 3 - 1;
            const int x = cx + e % 3 - 1;
            const bool ok = ((unsigned)z < GD) && ((unsigned)y < GD) && ((unsigned)x < GD);
            const int ci = (z * GD + y) * GD + x;
            int cn = ok ? (int)cntb[ci] : 0;
            cn = cn < CAPC ? cn : CAPC;          // overflow clamp (memory safety)
            A[e] = ci * CAPC - pre[e];
            pre[e + 1] = pre[e] + cn;
        }
        const int tot = pre[27];

        int cnt = 0;
        for (int g0 = 0; g0 < tot; g0 += 64) {
            const int g = g0 + lane;
            int adj = A[0];
            #pragma unroll
            for (int k = 1; k < 27; ++k) adj = (g >= pre[k]) ? A[k] : adj;
            const bool act = g < tot;
            const int ga = act ? (g + adj) : 0;
            const float4 p = lptsb[ga];            // coalesced stream
            const float d = c.w + p.w - 2.0f * (c.x * p.x + c.y * p.y + c.z * p.z);
            const bool h = act && (d < R2);
            const unsigned long long mk = __ballot(h);
            if (h) {
                const int pp = cnt + __popcll(mk & ltmask);
                if (pp < CAP) hit[pp] = listb[ga]; // id read only for hits
            }
            cnt += (int)__popcll(mk);
        }

        // ---- keep the 32 smallest original indices (set-equivalent to the
        // reference "first nsample in index order"; maxpool ignores order) ----
        if (cnt > KK) {
            const int stored = cnt < CAP ? cnt : CAP;
            int v[CAPL];
            #pragma unroll
            for (int j = 0; j < CAPL; ++j) {
                const int q = j * 64 + lane;
                const int val = hit[q];            // within allocated LDS
                v[j] = (q < stored) ? val : 0x7fffffff;
            }
            int lo = 0, hi = NN - 1;
            while (lo < hi) {                      // wave-uniform, <=14 iters
                const int mid = (lo + hi) >> 1;
                int cle = 0;
                #pragma unroll
                for (int j = 0; j < CAPL; ++j)
                    if (j * 64 < stored)           // wave-uniform chunk gate
                        cle += (int)__popcll(__ballot(v[j] <= mid));
                if (cle >= KK) hi = mid; else lo = mid + 1;
            }
            int pos = 0;                           // exactly KK selected (ids unique)
            #pragma unroll
            for (int j = 0; j < CAPL; ++j) {
                if (j * 64 < stored) {
                    const bool sel = v[j] <= lo;
                    const unsigned long long mk = __ballot(sel);
                    if (sel) hit[pos + __popcll(mk & ltmask)] = v[j];
                    pos += (int)__popcll(mk);
                }
            }
        } else if (lane < KK) {
            const int vv = (cnt == 0) ? 0 : ((lane < cnt) ? hit[lane] : hit[0]);
            hit[lane] = vv;
        }
    }

    // ================= gather: sid (LDS) -> rows -> LDS =================
    {
        const int sid = hit[m];                  // wave-private, program order
        const ushort* src = fbase + (size_t)sid * 64 + half * 32;
        ushort* dst = gbuf + m * 104 + half * 32;
        uint4 rows[4];
        #pragma unroll
        for (int i = 0; i < 4; ++i) rows[i] = *(const uint4*)(src + i * 8);
        const float4 p = pb[sid];
        const float4 cc = pb[s];
        #pragma unroll
        for (int i = 0; i < 4; ++i) *(uint4*)(dst + i * 8) = rows[i];
        if (half == 0) {
            bf16x8 rel = {(__bf16)(p.x - cc.x), (__bf16)(p.y - cc.y),
                          (__bf16)(p.z - cc.z), (__bf16)0.f,
                          (__bf16)0.f, (__bf16)0.f, (__bf16)0.f, (__bf16)0.f};
            *(bf16x8*)(gbuf + m * 104 + 64) = rel;
            *(uint4*)(gbuf + m * 104 + 88) = make_uint4(0, 0, 0, 0);
        } else {
            *(uint4*)(gbuf + m * 104 + 72) = make_uint4(0, 0, 0, 0);
            *(uint4*)(gbuf + m * 104 + 80) = make_uint4(0, 0, 0, 0);
        }
    }

    // ================= layer 1: [32x96]x[96x64] =================
    {
        f32x4 acc[2][4];
        #pragma unroll
        for (int nt = 0; nt < 4; ++nt) {
            const float bv = b1[nt * 16 + mrow];
            acc[0][nt] = (f32x4){bv, bv, bv, bv};
            acc[1][nt] = acc[0][nt];
        }
        #pragma unroll
        for (int ks = 0; ks < 3; ++ks) {
            const bf16x8 a0 = *(const bf16x8*)(gbuf + mrow * 104 + ks * 32 + quad * 8);
            const bf16x8 a1 = *(const bf16x8*)(gbuf + (16 + mrow) * 104 + ks * 32 + quad * 8);
            #pragma unroll
            for (int nt = 0; nt < 4; ++nt) {
                const bf16x8 wf = *(const bf16x8*)(W1t + (nt * 16 + mrow) * 96 + ks * 32 + quad * 8);
                acc[0][nt] = MFMA(a0, wf, acc[0][nt]);
                acc[1][nt] = MFMA(a1, wf, acc[1][nt]);
            }
        }
        #pragma unroll
        for (int mt = 0; mt < 2; ++mt)
            #pragma unroll
            for (int nt = 0; nt < 4; ++nt)
                #pragma unroll
                for (int r = 0; r < 4; ++r)
                    gbuf[(mt * 16 + quad * 4 + r) * 104 + nt * 16 + mrow] =
                        f2bf(fmaxf(acc[mt][nt][r], 0.0f));
    }

    // ================= layer 2: [32x64]x[64x64] =================
    {
        f32x4 acc[2][4];
        #pragma unroll
        for (int nt = 0; nt < 4; ++nt) {
            const float bv = b2[nt * 16 + mrow];
            acc[0][nt] = (f32x4){bv, bv, bv, bv};
            acc[1][nt] = acc[0][nt];
        }
        #pragma unroll
        for (int ks = 0; ks < 2; ++ks) {
            const bf16x8 a0 = *(const bf16x8*)(gbuf + mrow * 104 + ks * 32 + quad * 8);
            const bf16x8 a1 = *(const bf16x8*)(gbuf + (16 + mrow) * 104 + ks * 32 + quad * 8);
            #pragma unroll
            for (int nt = 0; nt < 4; ++nt) {
                const bf16x8 wf = *(const bf16x8*)(W2t + (nt * 16 + mrow) * 64 + ks * 32 + quad * 8);
                acc[0][nt] = MFMA(a0, wf, acc[0][nt]);
                acc[1][nt] = MFMA(a1, wf, acc[1][nt]);
            }
        }
        #pragma unroll
        for (int mt = 0; mt < 2; ++mt)
            #pragma unroll
            for (int nt = 0; nt < 4; ++nt)
                #pragma unroll
                for (int r = 0; r < 4; ++r)
                    gbuf[(mt * 16 + quad * 4 + r) * 104 + nt * 16 + mrow] =
                        f2bf(fmaxf(acc[mt][nt][r], 0.0f));
    }

    // ============ layer 3: [32x64]x[64x128] two n-halves + maxpool ==========
    #pragma unroll
    for (int nh = 0; nh < 2; ++nh) {
        f32x4 acc[2][4];
        #pragma unroll
        for (int ntl = 0; ntl < 4; ++ntl) {
            const float bv = b3[(nh * 4 + ntl) * 16 + mrow];
            acc[0][ntl] = (f32x4){bv, bv, bv, bv};
            acc[1][ntl] = acc[0][ntl];
        }
        #pragma unroll
        for (int ks = 0; ks < 2; ++ks) {
            const bf16x8 a0 = *(const bf16x8*)(gbuf + mrow * 104 + ks * 32 + quad * 8);
            const bf16x8 a1 = *(const bf16x8*)(gbuf + (16 + mrow) * 104 + ks * 32 + quad * 8);
            #pragma unroll
            for (int ntl = 0; ntl < 4; ++ntl) {
                const bf16x8 wf = *(const bf16x8*)(
                    W3t + ((nh * 4 + ntl) * 16 + mrow) * 64 + ks * 32 + quad * 8);
                acc[0][ntl] = MFMA(a0, wf, acc[0][ntl]);
                acc[1][ntl] = MFMA(a1, wf, acc[1][ntl]);
            }
        }
        #pragma unroll
        for (int ntl = 0; ntl < 4; ++ntl) {
            const f32x4 v0 = acc[0][ntl], v1 = acc[1][ntl];
            float mx = fmaxf(fmaxf(v0[0], v0[1]), fmaxf(v0[2], v0[3]));
            mx = fmaxf(mx, fmaxf(fmaxf(v1[0], v1[1]), fmaxf(v1[2], v1[3])));
            mx = fmaxf(mx, __shfl_xor(mx, 16));
            mx = fmaxf(mx, __shfl_xor(mx, 32));
            mx = fmaxf(mx, 0.0f);
            if (quad == 0) stage[(nh * 4 + ntl) * 16 + mrow][w] = mx;
        }
    }
    __syncthreads();

    // ---- epilogue: 128 ch x 4 s, float2 per thread -------------------------
    {
        const int ch = threadIdx.x & 127;
        const int hf = threadIdx.x >> 7;           // 0/1
        float* dst = out_feat + ((size_t)b * 128 + ch) * SS + s0 + hf * 2;
        *(float2*)dst = make_float2(stage[ch][hf * 2], stage[ch][hf * 2 + 1]);
    }
}

// ---------------------------------------------------------------------------
extern "C" void kernel_launch(void* const* d_in, const int* in_sizes, int n_in,
                              void* d_out, int out_size, void* d_ws, size_t ws_size,
                              hipStream_t stream) {
    const float* xyz  = (const float*)d_in[0];
    const float* feat = (const float*)d_in[1];
    const float* W1   = (const float*)d_in[2];
    const float* b1   = (const float*)d_in[3];
    const float* W2   = (const float*)d_in[4];
    const float* b2   = (const float*)d_in[5];
    const float* W3   = (const float*)d_in[6];
    const float* b3   = (const float*)d_in[7];

    float* out      = (float*)d_out;
    float* out_xyz  = out;                               // [2,4096,3]
    float* out_feat = out + (size_t)BB * SS * 3;         // [2,128,4096]
    float* out_sidx = out_feat + (size_t)BB * 128 * SS;  // [2,4096]

    char* ws = (char*)d_ws;
    float4* pts4    = (float4*)(ws + WS_PTS4);
    ushort* feat_nc = (ushort*)(ws + WS_FEAT);
    ushort* W1t     = (ushort*)(ws + WS_W1T);
    ushort* W2t     = (ushort*)(ws + WS_W2T);
    ushort* W3t     = (ushort*)(ws + WS_W3T);
    uint*   counts  = (uint*)(ws + WS_CNT);
    int*    list    = (int*)(ws + WS_LIST);
    float4* lpts    = (float4*)(ws + WS_LPTS);

    hipMemsetAsync(counts, 0, (size_t)BB * GC * 4, stream);
    prep_kernel<<<NBLK, 256, 0, stream>>>(
        xyz, feat, W1, W2, W3, pts4, feat_nc, W1t, W2t, W3t, out_xyz, out_sidx,
        counts, list, lpts);
    fused_kernel<<<BB * SS / 4, 256, 0, stream>>>(pts4, feat_nc, counts, list,
                                                  lpts, W1t, W2t, W3t,
                                                  b1, b2, b3, out_feat);
}

// Round 8
// 139.875 us; speedup vs baseline: 3.7726x; 1.0337x over previous
//
#include <hip/hip_runtime.h>

#define BB 2
#define NN 16384
#define CC 64
#define SS 4096
#define KK 32
#define R2 0.16f   // RADIUS^2

// spatial grid: cell = RADIUS, 24^3 cells covering [-4.8, 4.8] (clamped; the
// clamp is monotone so the 3x3x3 neighborhood remains a superset of the ball
// for ANY input magnitude — tail points just pile into edge cells)
#define GD   24
#define GC   (GD * GD * GD)       // 13824 cells per batch
#define CAPC 112                  // per-cell bucket capacity (center cell ~66)
#define CAP  512                  // per-wave hit-list capacity (max expected ~360)
#define CAPL (CAP / 64)           // 8 register chunks for selection

typedef __bf16 bf16x8 __attribute__((ext_vector_type(8)));
typedef float  f32x4  __attribute__((ext_vector_type(4)));

#define MFMA(a, b, c) __builtin_amdgcn_mfma_f32_16x16x32_bf16((a), (b), (c), 0, 0, 0)

static __device__ __forceinline__ ushort f2bf(float f) {
    __bf16 h = (__bf16)f;
    return *(ushort*)&h;
}

static __device__ __forceinline__ int cellc(float x) {
    int i = (int)floorf(x * 2.5f + 12.0f);
    return i < 0 ? 0 : (i > GD - 1 ? GD - 1 : i);
}

// workspace section offsets (bytes), all 16B aligned
#define WS_PTS4   0          // pts4:    2*16384*16    =   524,288
#define WS_FEAT   524288     // feat_nc: 2*16384*64*2  = 4,194,304
#define WS_W1T    4718592    // 64*96*2   = 12,288
#define WS_W2T    4730880    // 64*64*2   =  8,192
#define WS_W3T    4739072    // 128*64*2  = 16,384
#define WS_CNT    4755456    // counts: 2*13824*4 = 110,592
#define WS_LPTS   4866048    // coord+id buckets: 2*13824*112*16 = 49,545,216
                             // (end 54,411,264; id packed in .w — no list[])

// prep index ranges (block-granular: T_SIDX = 328 blocks exactly)
#define T_PTS   (BB * NN)                  // 32768
#define T_W1    (T_PTS + 64 * 96)          // 38912
#define T_W2    (T_W1 + 64 * 64)           // 43008
#define T_W3    (T_W2 + 128 * 64)          // 51200
#define T_NXYZ  (T_W3 + BB * SS * 3)       // 75776
#define T_SIDX  (T_NXYZ + BB * SS)         // 83968 = 328*256
#define FEAT_B0 (T_SIDX / 256)             // 328: first feat-transpose block
#define NBLK    (FEAT_B0 + BB * (NN / 32)) // 328 + 1024 = 1352 blocks

// ---------------------------------------------------------------------------
// prep: pts4=(x,y,z,|x|^2) + coordinate+id-carrying per-cell bucket insert;
// bf16 weight transposes; coalesced new_xyz copy; samp_idx; feat [B][C][N]
// fp32 -> [B][N][C] bf16 via LDS-tiled transpose (blocks >= FEAT_B0). One
// wide launch.
// ---------------------------------------------------------------------------
__global__ __launch_bounds__(256) void prep_kernel(
        const float* __restrict__ xyz, const float* __restrict__ feat,
        const float* __restrict__ W1, const float* __restrict__ W2,
        const float* __restrict__ W3,
        float4* __restrict__ pts4, ushort* __restrict__ feat_nc,
        ushort* __restrict__ W1t, ushort* __restrict__ W2t,
        ushort* __restrict__ W3t,
        float* __restrict__ out_xyz, float* __restrict__ out_sidx,
        uint* __restrict__ counts, float4* __restrict__ lpts) {
    if (blockIdx.x >= FEAT_B0) {
        // ---- LDS-tiled feat transpose: one 64ch x 32pt tile per block ----
        __shared__ float tile[64][33];                 // +1 pad
        const int g = blockIdx.x - FEAT_B0;            // 0..1023
        const int b = g >> 9, n0 = (g & 511) << 5;
        const int t = threadIdx.x;
        const float* fb = feat + (size_t)b * CC * NN + n0;
        #pragma unroll
        for (int cc = 0; cc < 8; ++cc) {
            const int c = cc * 8 + (t >> 5);
            tile[c][t & 31] = fb[(size_t)c * NN + (t & 31)];
        }
        __syncthreads();
        const int p = t >> 3, c8 = t & 7;
        uint u[4];
        #pragma unroll
        for (int q = 0; q < 4; ++q) {
            u[q] = (uint)f2bf(tile[c8 * 8 + 2 * q][p]) |
                   ((uint)f2bf(tile[c8 * 8 + 2 * q + 1][p]) << 16);
        }
        *(uint4*)(feat_nc + ((size_t)b * NN + n0 + p) * 64 + c8 * 8) =
            make_uint4(u[0], u[1], u[2], u[3]);
        return;
    }
    const int t = blockIdx.x * 256 + threadIdx.x;
    if (t < T_PTS) {
        const float* p = xyz + (size_t)t * 3;
        const float x = p[0], y = p[1], z = p[2];
        pts4[t] = make_float4(x, y, z, x * x + y * y + z * z);
        const int cell = (cellc(z) * GD + cellc(y)) * GD + cellc(x);
        const int b = t >> 14, n = t & (NN - 1);
        const uint rank = atomicAdd(&counts[(size_t)b * GC + cell], 1u);
        if (rank < CAPC) {
            const size_t slot = ((size_t)b * GC + cell) * CAPC + rank;
            lpts[slot] = make_float4(x, y, z, __int_as_float(n));
        }
    } else if (t < T_W1) {
        const int i = t - T_PTS;
        const int n = i / 96, k = i - n * 96;
        float v = 0.0f;
        if (k < 64) v = W1[(3 + k) * 64 + n];
        else if (k < 67) v = W1[(k - 64) * 64 + n];
        W1t[n * 96 + k] = f2bf(v);
    } else if (t < T_W2) {
        const int i = t - T_W1;
        const int n = i >> 6, k = i & 63;
        W2t[n * 64 + k] = f2bf(W2[k * 64 + n]);
    } else if (t < T_W3) {
        const int i = t - T_W2;
        const int n = i >> 6, k = i & 63;
        W3t[n * 64 + k] = f2bf(W3[k * 128 + n]);
    } else if (t < T_NXYZ) {
        const int i = t - T_W3;              // new_xyz = xyz[:, :SS] copy
        const int b = i / (SS * 3), j = i - b * (SS * 3);
        out_xyz[i] = xyz[(size_t)b * NN * 3 + j];
    } else if (t < T_SIDX) {
        const int i = t - T_NXYZ;
        out_sidx[i] = (float)(i & (SS - 1));
    }
}

// per-lane 27-way segment select (pre/A constant-indexed, rule-#20 safe)
#define ADJ27(gq, adjv) do { adjv = A[0];                                   \
    _Pragma("unroll")                                                       \
    for (int k_ = 1; k_ < 27; ++k_) adjv = ((gq) >= pre[k_]) ? A[k_] : adjv;\
} while (0)

// ---------------------------------------------------------------------------
// fused: one wave = one centroid. Ball query over the 3x3x3 neighbor cells
// with EXACT cell-vs-ball pruning (cells whose box can't intersect the ball
// are dropped — ~halves the candidate stream; +1e-3 margin guards fp32
// cancellation in the expanded distance). Flattened candidate loop with a
// 2-deep load pipeline (prefetch next 64 entries while testing current).
// Entries carry (x,y,z,id) — |p|^2 recomputed via FMA, no second array.
// Selection of the 32 smallest ids via ballot-popcount binary search.
// Then gather + 3-layer MLP + maxpool (proven body); the maxpool stage
// lives in the free 16B row-tails of each wave's gbuf (LDS 29184->26624,
// 6 blocks/CU resident).
// ---------------------------------------------------------------------------
__global__ __launch_bounds__(256, 2) void fused_kernel(
        const float4* __restrict__ pts4, const ushort* __restrict__ feat_nc,
        const uint* __restrict__ counts, const float4* __restrict__ lpts,
        const ushort* __restrict__ W1t, const ushort* __restrict__ W2t,
        const ushort* __restrict__ W3t,
        const float* __restrict__ b1, const float* __restrict__ b2,
        const float* __restrict__ b3, float* __restrict__ out_feat) {
    const int w = threadIdx.x >> 6, lane = threadIdx.x & 63;
    const int quad = lane >> 4, mrow = lane & 15;
    const int m = lane & 31, half = lane >> 5;

    __shared__ __align__(16) ushort ldsA[4][32 * 104];   // hits -> g -> h1 -> h2 (+tails)
    ushort* gbuf = ldsA[w];
    int* hit = (int*)gbuf;                               // 2KB bq scratch (CAP ints)

    const int xcd = blockIdx.x & 7;
    const int slot = blockIdx.x >> 3;              // 0..255
    const int b = xcd >> 2;
    const int s0 = ((xcd & 3) * 256 + slot) * 4;   // block's 4-s tile
    const int s = s0 + w;

    const float4* pb = pts4 + (size_t)b * NN;
    const ushort* fbase = feat_nc + (size_t)b * NN * 64;
    const unsigned long long ltmask = (1ull << lane) - 1ull;

    // ================= ball query via pruned cell buckets =================
    {
        const float4 c = pb[s];
        const int cx = cellc(c.x), cy = cellc(c.y), cz = cellc(c.z);
        const uint* cntb = counts + (size_t)b * GC;
        const float4* lptsb = lpts + (size_t)b * GC * CAPC;

        int pre[28], A[27];
        pre[0] = 0;
        #pragma unroll
        for (int e = 0; e < 27; ++e) {
            const int z = cz + e / 9 - 1;
            const int y = cy + (e / 3) % 3 - 1;
            const int x = cx + e % 3 - 1;
            const bool ok = ((unsigned)z < GD) && ((unsigned)y < GD) && ((unsigned)x < GD);
            const int ci = (z * GD + y) * GD + x;
            // exact cell-box vs ball test (edge cells unbounded on clamped side)
            const float bx0 = (x <= 0)      ? -1e30f : (x - 12) * 0.4f;
            const float bx1 = (x >= GD - 1) ?  1e30f : (x - 11) * 0.4f;
            const float by0 = (y <= 0)      ? -1e30f : (y - 12) * 0.4f;
            const float by1 = (y >= GD - 1) ?  1e30f : (y - 11) * 0.4f;
            const float bz0 = (z <= 0)      ? -1e30f : (z - 12) * 0.4f;
            const float bz1 = (z >= GD - 1) ?  1e30f : (z - 11) * 0.4f;
            const float dx = fmaxf(fmaxf(bx0 - c.x, c.x - bx1), 0.0f);
            const float dy = fmaxf(fmaxf(by0 - c.y, c.y - by1), 0.0f);
            const float dz = fmaxf(fmaxf(bz0 - c.z, c.z - bz1), 0.0f);
            const bool reach = (dx * dx + dy * dy + dz * dz) < (R2 + 1e-3f);
            int cn = (ok && reach) ? (int)cntb[ok ? ci : 0] : 0;
            cn = cn < CAPC ? cn : CAPC;          // overflow clamp (memory safety)
            A[e] = ci * CAPC - pre[e];
            pre[e + 1] = pre[e] + cn;
        }
        const int tot = pre[27];

        int cnt = 0;
        float4 pc;
        {
            const int g = lane;
            int adj; ADJ27(g, adj);
            pc = lptsb[(g < tot) ? (g + adj) : 0];
        }
        for (int g0 = 0; g0 < tot; g0 += 64) {
            float4 pn;                           // prefetch next 64 entries
            {
                const int gn = g0 + 64 + lane;
                int adjn; ADJ27(gn, adjn);
                pn = lptsb[(gn < tot) ? (gn + adjn) : 0];
            }
            const bool act = (g0 + lane) < tot;
            const float pw = pc.x * pc.x + pc.y * pc.y + pc.z * pc.z;
            const float d = c.w + pw - 2.0f * (c.x * pc.x + c.y * pc.y + c.z * pc.z);
            const bool h = act && (d < R2);
            const unsigned long long mk = __ballot(h);
            if (h) {
                const int pp = cnt + __popcll(mk & ltmask);
                if (pp < CAP) hit[pp] = __float_as_int(pc.w);
            }
            cnt += (int)__popcll(mk);
            pc = pn;
        }

        // ---- keep the 32 smallest original indices (set-equivalent to the
        // reference "first nsample in index order"; maxpool ignores order) ----
        if (cnt > KK) {
            const int stored = cnt < CAP ? cnt : CAP;
            int v[CAPL];
            #pragma unroll
            for (int j = 0; j < CAPL; ++j) {
                const int q = j * 64 + lane;
                const int val = hit[q];            // within allocated LDS
                v[j] = (q < stored) ? val : 0x7fffffff;
            }
            int lo = 0, hi = NN - 1;
            while (lo < hi) {                      // wave-uniform, <=14 iters
                const int mid = (lo + hi) >> 1;
                int cle = 0;
                #pragma unroll
                for (int j = 0; j < CAPL; ++j)
                    if (j * 64 < stored)           // wave-uniform chunk gate
                        cle += (int)__popcll(__ballot(v[j] <= mid));
                if (cle >= KK) hi = mid; else lo = mid + 1;
            }
            int pos = 0;                           // exactly KK selected (ids unique)
            #pragma unroll
            for (int j = 0; j < CAPL; ++j) {
                if (j * 64 < stored) {
                    const bool sel = v[j] <= lo;
                    const unsigned long long mk = __ballot(sel);
                    if (sel) hit[pos + __popcll(mk & ltmask)] = v[j];
                    pos += (int)__popcll(mk);
                }
            }
        } else if (lane < KK) {
            const int vv = (cnt == 0) ? 0 : ((lane < cnt) ? hit[lane] : hit[0]);
            hit[lane] = vv;
        }
    }

    // ================= gather: sid (LDS) -> rows -> LDS =================
    {
        const int sid = hit[m];                  // wave-private, program order
        const ushort* src = fbase + (size_t)sid * 64 + half * 32;
        ushort* dst = gbuf + m * 104 + half * 32;
        uint4 rows[4];
        #pragma unroll
        for (int i = 0; i < 4; ++i) rows[i] = *(const uint4*)(src + i * 8);
        const float4 p = pb[sid];
        const float4 cc = pb[s];
        #pragma unroll
        for (int i = 0; i < 4; ++i) *(uint4*)(dst + i * 8) = rows[i];
        if (half == 0) {
            bf16x8 rel = {(__bf16)(p.x - cc.x), (__bf16)(p.y - cc.y),
                          (__bf16)(p.z - cc.z), (__bf16)0.f,
                          (__bf16)0.f, (__bf16)0.f, (__bf16)0.f, (__bf16)0.f};
            *(bf16x8*)(gbuf + m * 104 + 64) = rel;
            *(uint4*)(gbuf + m * 104 + 88) = make_uint4(0, 0, 0, 0);
        } else {
            *(uint4*)(gbuf + m * 104 + 72) = make_uint4(0, 0, 0, 0);
            *(uint4*)(gbuf + m * 104 + 80) = make_uint4(0, 0, 0, 0);
        }
    }

    // ================= layer 1: [32x96]x[96x64] =================
    {
        f32x4 acc[2][4];
        #pragma unroll
        for (int nt = 0; nt < 4; ++nt) {
            const float bv = b1[nt * 16 + mrow];
            acc[0][nt] = (f32x4){bv, bv, bv, bv};
            acc[1][nt] = acc[0][nt];
        }
        #pragma unroll
        for (int ks = 0; ks < 3; ++ks) {
            const bf16x8 a0 = *(const bf16x8*)(gbuf + mrow * 104 + ks * 32 + quad * 8);
            const bf16x8 a1 = *(const bf16x8*)(gbuf + (16 + mrow) * 104 + ks * 32 + quad * 8);
            #pragma unroll
            for (int nt = 0; nt < 4; ++nt) {
                const bf16x8 wf = *(const bf16x8*)(W1t + (nt * 16 + mrow) * 96 + ks * 32 + quad * 8);
                acc[0][nt] = MFMA(a0, wf, acc[0][nt]);
                acc[1][nt] = MFMA(a1, wf, acc[1][nt]);
            }
        }
        #pragma unroll
        for (int mt = 0; mt < 2; ++mt)
            #pragma unroll
            for (int nt = 0; nt < 4; ++nt)
                #pragma unroll
                for (int r = 0; r < 4; ++r)
                    gbuf[(mt * 16 + quad * 4 + r) * 104 + nt * 16 + mrow] =
                        f2bf(fmaxf(acc[mt][nt][r], 0.0f));
    }

    // ================= layer 2: [32x64]x[64x64] =================
    {
        f32x4 acc[2][4];
        #pragma unroll
        for (int nt = 0; nt < 4; ++nt) {
            const float bv = b2[nt * 16 + mrow];
            acc[0][nt] = (f32x4){bv, bv, bv, bv};
            acc[1][nt] = acc[0][nt];
        }
        #pragma unroll
        for (int ks = 0; ks < 2; ++ks) {
            const bf16x8 a0 = *(const bf16x8*)(gbuf + mrow * 104 + ks * 32 + quad * 8);
            const bf16x8 a1 = *(const bf16x8*)(gbuf + (16 + mrow) * 104 + ks * 32 + quad * 8);
            #pragma unroll
            for (int nt = 0; nt < 4; ++nt) {
                const bf16x8 wf = *(const bf16x8*)(W2t + (nt * 16 + mrow) * 64 + ks * 32 + quad * 8);
                acc[0][nt] = MFMA(a0, wf, acc[0][nt]);
                acc[1][nt] = MFMA(a1, wf, acc[1][nt]);
            }
        }
        #pragma unroll
        for (int mt = 0; mt < 2; ++mt)
            #pragma unroll
            for (int nt = 0; nt < 4; ++nt)
                #pragma unroll
                for (int r = 0; r < 4; ++r)
                    gbuf[(mt * 16 + quad * 4 + r) * 104 + nt * 16 + mrow] =
                        f2bf(fmaxf(acc[mt][nt][r], 0.0f));
    }

    // ============ layer 3: [32x64]x[64x128] two n-halves + maxpool ==========
    // maxpool results go to the free 16B tail of each gbuf row (bytes 192-207;
    // L2/L3 MFMA reads touch only cols 0-63) — replaces the separate stage[].
    #pragma unroll
    for (int nh = 0; nh < 2; ++nh) {
        f32x4 acc[2][4];
        #pragma unroll
        for (int ntl = 0; ntl < 4; ++ntl) {
            const float bv = b3[(nh * 4 + ntl) * 16 + mrow];
            acc[0][ntl] = (f32x4){bv, bv, bv, bv};
            acc[1][ntl] = acc[0][ntl];
        }
        #pragma unroll
        for (int ks = 0; ks < 2; ++ks) {
            const bf16x8 a0 = *(const bf16x8*)(gbuf + mrow * 104 + ks * 32 + quad * 8);
            const bf16x8 a1 = *(const bf16x8*)(gbuf + (16 + mrow) * 104 + ks * 32 + quad * 8);
            #pragma unroll
            for (int ntl = 0; ntl < 4; ++ntl) {
                const bf16x8 wf = *(const bf16x8*)(
                    W3t + ((nh * 4 + ntl) * 16 + mrow) * 64 + ks * 32 + quad * 8);
                acc[0][ntl] = MFMA(a0, wf, acc[0][ntl]);
                acc[1][ntl] = MFMA(a1, wf, acc[1][ntl]);
            }
        }
        #pragma unroll
        for (int ntl = 0; ntl < 4; ++ntl) {
            const f32x4 v0 = acc[0][ntl], v1 = acc[1][ntl];
            float mx = fmaxf(fmaxf(v0[0], v0[1]), fmaxf(v0[2], v0[3]));
            mx = fmaxf(mx, fmaxf(fmaxf(v1[0], v1[1]), fmaxf(v1[2], v1[3])));
            mx = fmaxf(mx, __shfl_xor(mx, 16));
            mx = fmaxf(mx, __shfl_xor(mx, 32));
            mx = fmaxf(mx, 0.0f);
            if (quad == 0) {
                const int ch = (nh * 4 + ntl) * 16 + mrow;
                *(float*)((char*)gbuf + (ch >> 2) * 208 + 192 + (ch & 3) * 4) = mx;
            }
        }
    }
    __syncthreads();

    // ---- epilogue: 128 ch x 4 s, float2 per thread (reads gbuf tails) ----
    {
        const int ch = threadIdx.x & 127;
        const int hf = threadIdx.x >> 7;           // 0/1
        const int tb = (ch >> 2) * 208 + 192 + (ch & 3) * 4;
        const float v0 = *(const float*)((const char*)ldsA[hf * 2] + tb);
        const float v1 = *(const float*)((const char*)ldsA[hf * 2 + 1] + tb);
        float* dst = out_feat + ((size_t)b * 128 + ch) * SS + s0 + hf * 2;
        *(float2*)dst = make_float2(v0, v1);
    }
}

// ---------------------------------------------------------------------------
extern "C" void kernel_launch(void* const* d_in, const int* in_sizes, int n_in,
                              void* d_out, int out_size, void* d_ws, size_t ws_size,
                              hipStream_t stream) {
    const float* xyz  = (const float*)d_in[0];
    const float* feat = (const float*)d_in[1];
    const float* W1   = (const float*)d_in[2];
    const float* b1   = (const float*)d_in[3];
    const float* W2   = (const float*)d_in[4];
    const float* b2   = (const float*)d_in[5];
    const float* W3   = (const float*)d_in[6];
    const float* b3   = (const float*)d_in[7];

    float* out      = (float*)d_out;
    float* out_xyz  = out;                               // [2,4096,3]
    float* out_feat = out + (size_t)BB * SS * 3;         // [2,128,4096]
    float* out_sidx = out_feat + (size_t)BB * 128 * SS;  // [2,4096]

    char* ws = (char*)d_ws;
    float4* pts4    = (float4*)(ws + WS_PTS4);
    ushort* feat_nc = (ushort*)(ws + WS_FEAT);
    ushort* W1t     = (ushort*)(ws + WS_W1T);
    ushort* W2t     = (ushort*)(ws + WS_W2T);
    ushort* W3t     = (ushort*)(ws + WS_W3T);
    uint*   counts  = (uint*)(ws + WS_CNT);
    float4* lpts    = (float4*)(ws + WS_LPTS);

    hipMemsetAsync(counts, 0, (size_t)BB * GC * 4, stream);
    prep_kernel<<<NBLK, 256, 0, stream>>>(
        xyz, feat, W1, W2, W3, pts4, feat_nc, W1t, W2t, W3t, out_xyz, out_sidx,
        counts, lpts);
    fused_kernel<<<BB * SS / 4, 256, 0, stream>>>(pts4, feat_nc, counts, lpts,
                                                  W1t, W2t, W3t, b1, b2, b3,
                                                  out_feat);
}